// Round 1
// baseline (15259.267 us; speedup 1.0000x reference)
//
#include <hip/hip_runtime.h>
#include <math.h>

#define BB 64
#define SS 512
#define EE 256
#define HH 512

// ---------------------------------------------------------------------------
// Transpose 512x512: WT[k][j] = W[j][k]
// ---------------------------------------------------------------------------
__global__ __launch_bounds__(256) void k_transpose512(const float* __restrict__ W,
                                                      float* __restrict__ WT) {
    __shared__ __align__(16) float tile[32][33];
    int bx = blockIdx.x, by = blockIdx.y;
    int tx = threadIdx.x, ty = threadIdx.y; // (32, 8)
#pragma unroll
    for (int i = 0; i < 4; ++i) {
        int r = by * 32 + ty + 8 * i;
        tile[ty + 8 * i][tx] = W[r * HH + bx * 32 + tx];
    }
    __syncthreads();
#pragma unroll
    for (int i = 0; i < 4; ++i) {
        int r = bx * 32 + ty + 8 * i;
        WT[r * HH + by * 32 + tx] = tile[tx][ty + 8 * i];
    }
}

// ---------------------------------------------------------------------------
// Projection GEMM: out[m][n] = sum_k A[m][k] * Wih[n][k] + b1[n] + b2[n]
// A row m = (src ? emb[src[m]] : Ain + m*K).  M = BB*SS, N = HH.
// 64x64 tile per block, 256 threads, 4x4 micro-tile.
// ---------------------------------------------------------------------------
template <int K>
__global__ __launch_bounds__(256) void k_proj(const float* __restrict__ Ain,
                                              const int* __restrict__ src,
                                              const float* __restrict__ emb,
                                              const float* __restrict__ Wih,
                                              const float* __restrict__ b1,
                                              const float* __restrict__ b2,
                                              float* __restrict__ out) {
    __shared__ __align__(16) float As[16][68];
    __shared__ __align__(16) float Bs[16][68];
    int tid = threadIdx.x;
    int m0 = blockIdx.x * 64;
    int n0 = blockIdx.y * 64;
    int tx = tid & 15, ty = tid >> 4;
    int lr = tid >> 2;         // 0..63 row within tile (load)
    int lc = (tid & 3) * 4;    // 0,4,8,12 col offset (load)

    const float* arow;
    if (src) arow = emb + (size_t)src[m0 + lr] * EE;
    else     arow = Ain + (size_t)(m0 + lr) * K;
    const float* brow = Wih + (size_t)(n0 + lr) * K;

    float acc[4][4] = {};

    for (int k0 = 0; k0 < K; k0 += 16) {
        float4 av = *(const float4*)(arow + k0 + lc);
        float4 bv = *(const float4*)(brow + k0 + lc);
        __syncthreads();
        As[lc + 0][lr] = av.x; As[lc + 1][lr] = av.y;
        As[lc + 2][lr] = av.z; As[lc + 3][lr] = av.w;
        Bs[lc + 0][lr] = bv.x; Bs[lc + 1][lr] = bv.y;
        Bs[lc + 2][lr] = bv.z; Bs[lc + 3][lr] = bv.w;
        __syncthreads();
#pragma unroll
        for (int k = 0; k < 16; ++k) {
            float4 a = *(const float4*)&As[k][ty * 4];
            float4 b = *(const float4*)&Bs[k][tx * 4];
            acc[0][0] += a.x * b.x; acc[0][1] += a.x * b.y;
            acc[0][2] += a.x * b.z; acc[0][3] += a.x * b.w;
            acc[1][0] += a.y * b.x; acc[1][1] += a.y * b.y;
            acc[1][2] += a.y * b.z; acc[1][3] += a.y * b.w;
            acc[2][0] += a.z * b.x; acc[2][1] += a.z * b.y;
            acc[2][2] += a.z * b.z; acc[2][3] += a.z * b.w;
            acc[3][0] += a.w * b.x; acc[3][1] += a.w * b.y;
            acc[3][2] += a.w * b.z; acc[3][3] += a.w * b.w;
        }
    }

    int n = n0 + tx * 4;
    float bx_ = b1[n + 0] + b2[n + 0];
    float by_ = b1[n + 1] + b2[n + 1];
    float bz_ = b1[n + 2] + b2[n + 2];
    float bw_ = b1[n + 3] + b2[n + 3];
#pragma unroll
    for (int i = 0; i < 4; ++i) {
        int m = m0 + ty * 4 + i;
        float4 o;
        o.x = acc[i][0] + bx_; o.y = acc[i][1] + by_;
        o.z = acc[i][2] + bz_; o.w = acc[i][3] + bw_;
        *(float4*)(out + (size_t)m * HH + n) = o;
    }
}

// ---------------------------------------------------------------------------
// Recurrence: per block, 2 batch elements; h in LDS; WT streamed from L2.
// h_t = tanh(pre[b][t][:] + W_hh @ h_{t-1}),  y[b][t][:] = h_t
// Thread layout: batch = tid>>7, j0 = (tid&127)*4 (4 consecutive outputs).
// ---------------------------------------------------------------------------
__global__ __launch_bounds__(256) void k_rec(const float* __restrict__ pre,
                                             const float* __restrict__ WT,
                                             float* __restrict__ y,
                                             float* __restrict__ hlast) {
    __shared__ __align__(16) float h_sh[2][HH];
    int tid = threadIdx.x;
    int bl = tid >> 7;               // 0/1: local batch
    int j0 = (tid & 127) * 4;        // output columns
    int b = blockIdx.x * 2 + bl;

    *(float4*)&h_sh[bl][j0] = make_float4(0.f, 0.f, 0.f, 0.f);
    __syncthreads();

    const float* preb = pre + (size_t)b * SS * HH;
    float* yb = y + (size_t)b * SS * HH;
    const float* wp = WT + j0;
    const float* hb = h_sh[bl];
    float4 hn = make_float4(0.f, 0.f, 0.f, 0.f);

    for (int t = 0; t < SS; ++t) {
        float4 p = *(const float4*)(preb + (size_t)t * HH + j0); // early, hidden by k-loop
        float4 acc = make_float4(0.f, 0.f, 0.f, 0.f);
        const float* wk = wp;
#pragma unroll 4
        for (int k4 = 0; k4 < HH; k4 += 4) {
            float4 hk = *(const float4*)(hb + k4);      // LDS broadcast
            float4 w0 = *(const float4*)(wk);
            float4 w1 = *(const float4*)(wk + HH);
            float4 w2 = *(const float4*)(wk + 2 * HH);
            float4 w3 = *(const float4*)(wk + 3 * HH);
            wk += 4 * HH;
            acc.x += w0.x * hk.x; acc.y += w0.y * hk.x;
            acc.z += w0.z * hk.x; acc.w += w0.w * hk.x;
            acc.x += w1.x * hk.y; acc.y += w1.y * hk.y;
            acc.z += w1.z * hk.y; acc.w += w1.w * hk.y;
            acc.x += w2.x * hk.z; acc.y += w2.y * hk.z;
            acc.z += w2.z * hk.z; acc.w += w2.w * hk.z;
            acc.x += w3.x * hk.w; acc.y += w3.y * hk.w;
            acc.z += w3.z * hk.w; acc.w += w3.w * hk.w;
        }
        hn.x = tanhf(p.x + acc.x);
        hn.y = tanhf(p.y + acc.y);
        hn.z = tanhf(p.z + acc.z);
        hn.w = tanhf(p.w + acc.w);
        __syncthreads();                         // all reads of h done
        *(float4*)&h_sh[bl][j0] = hn;
        *(float4*)(yb + (size_t)t * HH + j0) = hn;
        __syncthreads();                         // h ready
    }
    *(float4*)(hlast + (size_t)b * HH + j0) = hn;
}

// ---------------------------------------------------------------------------
extern "C" void kernel_launch(void* const* d_in, const int* in_sizes, int n_in,
                              void* d_out, int out_size, void* d_ws, size_t ws_size,
                              hipStream_t stream) {
    const int*   src   = (const int*)d_in[0];
    const float* emb   = (const float*)d_in[1];
    const float* W_ih0 = (const float*)d_in[2];
    const float* W_hh0 = (const float*)d_in[3];
    const float* b_ih0 = (const float*)d_in[4];
    const float* b_hh0 = (const float*)d_in[5];
    const float* W_ih1 = (const float*)d_in[6];
    const float* W_hh1 = (const float*)d_in[7];
    const float* b_ih1 = (const float*)d_in[8];
    const float* b_hh1 = (const float*)d_in[9];

    float* out = (float*)d_out;
    float* y_out = out;                               // [B][S][H]
    float* hlast = out + (size_t)BB * SS * HH;        // [2][B][H]

    float* ws  = (float*)d_ws;
    float* pre = ws;                                  // [B][S][H]  (reused for both layers)
    float* WT0 = ws + (size_t)BB * SS * HH;           // [H][H]
    float* WT1 = WT0 + (size_t)HH * HH;

    // Transpose recurrent weights once per launch (cheap: 1 MB each)
    k_transpose512<<<dim3(16, 16), dim3(32, 8), 0, stream>>>(W_hh0, WT0);
    k_transpose512<<<dim3(16, 16), dim3(32, 8), 0, stream>>>(W_hh1, WT1);

    // Layer 0: pre0 = emb[src] @ W_ih0^T + b_ih0 + b_hh0
    k_proj<EE><<<dim3(512, 8), 256, 0, stream>>>(nullptr, src, emb, W_ih0,
                                                 b_ih0, b_hh0, pre);
    // Layer 0 recurrence: y0 staged in d_out's y1 region (rec1 overwrites later)
    k_rec<<<32, 256, 0, stream>>>(pre, WT0, y_out, hlast);

    // Layer 1: pre1 = y0 @ W_ih1^T + b_ih1 + b_hh1
    k_proj<HH><<<dim3(512, 8), 256, 0, stream>>>(y_out, nullptr, nullptr, W_ih1,
                                                 b_ih1, b_hh1, pre);
    // Layer 1 recurrence: y1 + h_last1
    k_rec<<<32, 256, 0, stream>>>(pre, WT1, y_out, hlast + (size_t)BB * HH);
}